// Round 1
// baseline (25.289 us; speedup 1.0000x reference)
//
#include <hip/hip_runtime.h>
#include <math.h>

#define NWAVES_TOTAL 2048
#define GRID_V 1000

__device__ __forceinline__ float rl(float v, int k) {
    return __int_as_float(__builtin_amdgcn_readlane(__float_as_int(v), k));
}
__device__ __forceinline__ float rcpf(float x) { return __builtin_amdgcn_rcpf(x); }

__global__ __launch_bounds__(256, 2) void phys_kernel(
    const float* __restrict__ x,
    const float* __restrict__ W1, const float* __restrict__ b1,
    const float* __restrict__ W2, const float* __restrict__ b2,
    const float* __restrict__ W3, const float* __restrict__ b3,
    const float* __restrict__ W4, const float* __restrict__ b4,
    const float* __restrict__ i0p, const float* __restrict__ alphap,
    float* __restrict__ out, int nrows)
{
    // skewed LDS table: invbase[s][v] = exp(+alpha_s*K*(V_v - E_s)) / i0_s
    __shared__ float tab[3][1032];
#define TB(s, vv) tab[s][(vv) + ((vv) >> 5)]

    const float KFRT = (float)(96485.33 / (8.314 * 298.15));
    const float EEQ0 = -0.11f, EEQ1 = 0.08f, EEQ2 = 0.0f;
    const float dV = 1.25f / 999.0f;

    float al0 = alphap[0], al1 = alphap[1], al2 = alphap[2];
    float io0 = i0p[0], io1 = i0p[1], io2 = i0p[2];

    for (int v = threadIdx.x; v < GRID_V; v += 256) {
        float Vv = -1.25f + (float)v * dV;
        int sk = v + (v >> 5);
        tab[0][sk] = expf(al0 * KFRT * (Vv - EEQ0)) / io0;
        tab[1][sk] = expf(al1 * KFRT * (Vv - EEQ1)) / io1;
        tab[2][sk] = expf(al2 * KFRT * (Vv - EEQ2)) / io2;
    }

    const int lane = threadIdx.x & 63;
    const int wid = threadIdx.x >> 6;

    // resident weight columns (per-lane VGPRs)
    float w1c[5], w2c[64], w3c[64], w4r[6];
#pragma unroll
    for (int k = 0; k < 5; k++) w1c[k] = W1[k * 64 + lane];
#pragma unroll
    for (int k = 0; k < 64; k++) w2c[k] = W2[k * 64 + lane];
#pragma unroll
    for (int k = 0; k < 64; k++) w3c[k] = W3[k * 64 + lane];
#pragma unroll
    for (int m = 0; m < 6; m++) w4r[m] = W4[lane * 6 + m];
    float b1j = b1[lane], b2j = b2[lane], b3j = b3[lane];
    float b40 = b4[0], b41 = b4[1], b42 = b4[2], b43 = b4[3], b44 = b4[4], b45 = b4[5];

    __syncthreads();

    int gw = blockIdx.x * 4 + wid;
    for (int r = gw; r < nrows; r += NWAVES_TOTAL) {
        const int row = __builtin_amdgcn_readfirstlane(r);
        const float* xr = x + (size_t)row * 5;
        float x0 = xr[0], x1 = xr[1], x2 = xr[2], x3 = xr[3], x4 = xr[4];

        // L1: 5 -> 64
        float h = fmaf(x4, w1c[4], fmaf(x3, w1c[3], fmaf(x2, w1c[2],
                  fmaf(x1, w1c[1], fmaf(x0, w1c[0], b1j)))));
        h = fmaxf(h, 0.0f);

        // L2: 64 -> 64 (readlane broadcast, 4 accumulators for ILP)
        float a0 = b2j, a1 = 0.f, a2 = 0.f, a3 = 0.f;
#pragma unroll
        for (int k = 0; k < 64; k += 4) {
            a0 = fmaf(rl(h, k + 0), w2c[k + 0], a0);
            a1 = fmaf(rl(h, k + 1), w2c[k + 1], a1);
            a2 = fmaf(rl(h, k + 2), w2c[k + 2], a2);
            a3 = fmaf(rl(h, k + 3), w2c[k + 3], a3);
        }
        float h2 = fmaxf((a0 + a1) + (a2 + a3), 0.0f);

        // L3: 64 -> 64
        a0 = b3j; a1 = 0.f; a2 = 0.f; a3 = 0.f;
#pragma unroll
        for (int k = 0; k < 64; k += 4) {
            a0 = fmaf(rl(h2, k + 0), w3c[k + 0], a0);
            a1 = fmaf(rl(h2, k + 1), w3c[k + 1], a1);
            a2 = fmaf(rl(h2, k + 2), w3c[k + 2], a2);
            a3 = fmaf(rl(h2, k + 3), w3c[k + 3], a3);
        }
        float h3 = fmaxf((a0 + a1) + (a2 + a3), 0.0f);

        // L4: 64 -> 6 via per-lane products + butterfly reduce
        float p0 = h3 * w4r[0], p1 = h3 * w4r[1], p2 = h3 * w4r[2];
        float p3 = h3 * w4r[3], p4 = h3 * w4r[4], p5 = h3 * w4r[5];
#pragma unroll
        for (int off = 32; off > 0; off >>= 1) {
            p0 += __shfl_xor(p0, off);
            p1 += __shfl_xor(p1, off);
            p2 += __shfl_xor(p2, off);
            p3 += __shfl_xor(p3, off);
            p4 += __shfl_xor(p4, off);
            p5 += __shfl_xor(p5, off);
        }
        float lat0 = p0 + b40, lat1 = p1 + b41, lat2 = p2 + b42;
        float lat3 = p3 + b43, lat4 = p4 + b44, lat5 = p5 + b45;

        // epilogue (uniform across lanes)
        float rr   = 4e-8f * __expf(lat0);
        float epsv = rcpf(1.0f + __expf(-lat1));
        float Kdl  = __expf(lat2);
        float Deff = 1.91e-9f * epsv * sqrtf(epsv);
        float Kgdl = Kdl * Deff * rcpf(rr);
        float S    = rcpf(Kgdl) + fabsf(x3) * rcpf((1.0f - epsv) * Deff);
        float il0  = S * (float)(1.0 / (2.0 * 96485.33 * 34.0));
        float il1  = S * (float)(1.0 / (12.0 * 96485.33 * 34.0));

        float t0 = 2.0f * lat3, t1 = 2.0f * lat4, t2 = 2.0f * lat5;
        float mx = fmaxf(t0, fmaxf(t1, t2));
        float e0 = __expf(t0 - mx), e1 = __expf(t1 - mx), e2 = __expf(t2 - mx);
        float se = e0 + e1 + e2;
        float it0 = se * rcpf(e0), it1 = se * rcpf(e1), it2 = se * rcpf(e2);

        auto itot = [&](int v) -> float {
            float q0 = fmaf(TB(0, v), it0, il0);
            float q1 = fmaf(TB(1, v), it1, il1);
            float q2 = TB(2, v) * it2;
            return rcpf(q0) + rcpf(q1) + rcpf(q2);
        };

        // two-step 64-ary search for first v with i_tot(v) <= 200 (monotone decreasing)
        int v1 = min(16 * lane, 999);
        unsigned long long m1 = __ballot(itot(v1) <= 200.0f);
        int idx;
        if (m1 == 0ull) {
            idx = 999;                       // all above 200 -> min |diff| at end
        } else {
            int f = (int)__builtin_ctzll(m1);
            if (f == 0) {
                idx = 0;                     // already below at v=0
            } else {
                int base = 16 * (f - 1) + 1;
                int v2 = min(base + (lane & 15), 999);
                unsigned long long m2 = __ballot(itot(v2) <= 200.0f) & 0xFFFFull;
                int vs = base + (int)__builtin_ctzll(m2);
                float da = itot(vs - 1) - 200.0f;  // > 0
                float db = 200.0f - itot(vs);      // >= 0
                idx = (da <= db) ? (vs - 1) : vs;  // tie -> earlier index (argmin-first)
            }
        }

        // selected currents -> faradaic efficiencies
        float q0 = fmaf(TB(0, idx), it0, il0);
        float q1 = fmaf(TB(1, idx), it1, il1);
        float q2 = TB(2, idx) * it2;
        float s0 = rcpf(q0), s1 = rcpf(q1), s2 = rcpf(q2);
        float inv = rcpf(s0 + s1 + s2);
        if (lane == 0) {
            float2 o;
            o.x = s1 * inv;   // fe[1]
            o.y = s0 * inv;   // fe[0]
            reinterpret_cast<float2*>(out)[row] = o;
        }
    }
#undef TB
}

extern "C" void kernel_launch(void* const* d_in, const int* in_sizes, int n_in,
                              void* d_out, int out_size, void* d_ws, size_t ws_size,
                              hipStream_t stream) {
    (void)n_in; (void)d_ws; (void)ws_size; (void)out_size;
    int nrows = in_sizes[0] / 5;
    phys_kernel<<<dim3(512), dim3(256), 0, stream>>>(
        (const float*)d_in[0],
        (const float*)d_in[1], (const float*)d_in[2],
        (const float*)d_in[3], (const float*)d_in[4],
        (const float*)d_in[5], (const float*)d_in[6],
        (const float*)d_in[7], (const float*)d_in[8],
        (const float*)d_in[9], (const float*)d_in[10],
        (float*)d_out, nrows);
}